// Round 9
// baseline (279.694 us; speedup 1.0000x reference)
//
#include <hip/hip_runtime.h>

// Problem constants
#define BN 32768
#define KN 5
#define LN 128
#define HN 3
#define ROWS (BN*KN)        // 163840
#define BK ROWS
#define MT 32               // rows per tile
#define TILES (ROWS/MT)     // 5120
#define WGS 512
#define TPW (TILES/WGS)     // 10 tiles per workgroup
#define THREADS 1024        // 16 waves: B-frags 40 regs/wave -> 4 waves/SIMD
#define ASTR 168            // A row stride bf16: [emb16|h128|zero16] + 8 pad
#define GSTR 132            // gate-buffer row stride (f32): 128 + 4 pad
#define LOG2E 1.44269504089f

using bf16x8 = __attribute__((ext_vector_type(8))) __bf16;
using bf16x2 = __attribute__((ext_vector_type(2))) __bf16;
using f32x4  = __attribute__((ext_vector_type(4))) float;
using u16x8  = __attribute__((ext_vector_type(8))) unsigned short;
using u16x4  = __attribute__((ext_vector_type(4))) unsigned short;

__device__ inline unsigned short f2bf(float x) {
    union { float f; unsigned u; } v; v.f = x;
    unsigned r = v.u + 0x7FFFu + ((v.u >> 16) & 1u);   // RNE
    return (unsigned short)(r >> 16);
}
#if __has_builtin(__builtin_amdgcn_cvt_pk_bf16_f32)
__device__ inline unsigned short f2bf_fast(float x) {
    union { bf16x2 v; unsigned short us[2]; } u;
    u.v = __builtin_amdgcn_cvt_pk_bf16_f32(x, x);
    return u.us[0];
}
#else
__device__ inline unsigned short f2bf_fast(float x) { return f2bf(x); }
#endif
__device__ inline float bf2f(unsigned short b) {
    union { unsigned u; float f; } v; v.u = ((unsigned)b) << 16; return v.f;
}
__device__ inline float sigm(float x) {
    return __builtin_amdgcn_rcpf(1.0f + __builtin_amdgcn_exp2f(-LOG2E * x));
}
__device__ inline f32x4 splat4(float x) { f32x4 r; r[0]=x; r[1]=x; r[2]=x; r[3]=x; return r; }

__global__ __launch_bounds__(THREADS)   // 1024 thr => compiler must fit 128 regs/wave
void wahead_kernel(const float* __restrict__ z,   const float* __restrict__ anchors,
                   const float* __restrict__ W1,  const float* __restrict__ b1,
                   const float* __restrict__ W2,  const float* __restrict__ b2,
                   const float* __restrict__ Wih, const float* __restrict__ Whh,
                   const float* __restrict__ bih, const float* __restrict__ bhh,
                   const float* __restrict__ Wp,  const float* __restrict__ bp,
                   const float* __restrict__ Wr,  const float* __restrict__ br,
                   float* __restrict__ out)
{
    __shared__ unsigned short sA[2 * MT * ASTR];   // ping-pong [emb|h|0] bf16, 21.5 KB
    __shared__ float sG[4 * MT * GSTR];            // gate preacts (scaled), f32, 67.6 KB
    __shared__ float sW1[32], sb1[16], sW2[16 * 17], sb2[16], sWp[128], sWr[384];

    const int tid  = threadIdx.x;
    const int v    = tid >> 6;       // wave 0..15: owns gate-cols [32v, 32v+32)
    const int lane = tid & 63;
    const int quad = lane >> 4;
    const int cc   = lane & 15;
    const int tg   = v >> 2;         // gate index of this wave (i,f,g,o)
    const int l0   = 32 * (v & 3);   // column offset within the gate

    // ---- stage small constant weights into LDS ----
    if (tid < 32)  sW1[tid] = W1[tid];
    if (tid < 16)  { sb1[tid] = b1[tid]; sb2[tid] = b2[tid]; }
    if (tid < 256) sW2[(tid >> 4) * 17 + (tid & 15)] = W2[tid];   // sW2[col*17+hh]
    if (tid < 128) sWp[tid] = Wp[tid];
    if (tid < 384) sWr[tid] = Wr[tid];

    // ---- this wave's B fragments: 2 n-tiles x 5 k-tiles (scales folded) ----
    // B layout (16x16x32): n = lane&15, k = quad*8 + j
    const float sc = (tg == 2) ? (2.0f * LOG2E) : (-LOG2E);
    bf16x8 Bf[2][5];
    float  biasv[2];
    #pragma unroll
    for (int nt = 0; nt < 2; ++nt) {
        const int n = 32 * v + nt * 16 + cc;     // global gate-col in [0,512)
        biasv[nt] = sc * (bih[n] + bhh[n]);
        #pragma unroll
        for (int kt = 0; kt < 5; ++kt) {
            const int k0 = kt * 32 + quad * 8;
            float w[8];
            if (k0 < 16) {
                const float4 p0 = *reinterpret_cast<const float4*>(Wih + n * 16 + k0);
                const float4 p1 = *reinterpret_cast<const float4*>(Wih + n * 16 + k0 + 4);
                w[0]=p0.x; w[1]=p0.y; w[2]=p0.z; w[3]=p0.w;
                w[4]=p1.x; w[5]=p1.y; w[6]=p1.z; w[7]=p1.w;
            } else if (k0 < 144) {
                const float4 p0 = *reinterpret_cast<const float4*>(Whh + n * 128 + (k0 - 16));
                const float4 p1 = *reinterpret_cast<const float4*>(Whh + n * 128 + (k0 - 16) + 4);
                w[0]=p0.x; w[1]=p0.y; w[2]=p0.z; w[3]=p0.w;
                w[4]=p1.x; w[5]=p1.y; w[6]=p1.z; w[7]=p1.w;
            } else {
                #pragma unroll
                for (int j = 0; j < 8; ++j) w[j] = 0.0f;
            }
            union { bf16x8 bv; unsigned short us[8]; } pk;
            #pragma unroll
            for (int j = 0; j < 8; ++j) pk.us[j] = f2bf(sc * w[j]);
            Bf[nt][kt] = pk.bv;
        }
    }

    const float bpv = bp[0];
    const float br0 = br[0], br1 = br[1], br2 = br[2];

    __syncthreads();   // consts staged

    const int erow = tid >> 5;   // 0..31 (32 threads per row)
    const int ej   = tid & 31;   // 0..31

    #pragma unroll 1
    for (int ti = 0; ti < TPW; ++ti) {
        const int tile = blockIdx.x * TPW + ti;
        const int r0g  = tile * MT;

        // -------- staging: emb MLP + zero-pad + z --------
        {
            const int gr = r0g + erow;
            if (ej < 16) {
                const float ax = anchors[gr * 2], ay = anchors[gr * 2 + 1];
                float acc_e = sb2[ej];
                #pragma unroll
                for (int hh = 0; hh < 16; ++hh) {
                    float pre = fmaf(sW1[hh * 2], ax, fmaf(sW1[hh * 2 + 1], ay, sb1[hh]));
                    pre = fmaxf(pre, 0.0f);
                    acc_e = fmaf(pre, sW2[ej * 17 + hh], acc_e);
                }
                const unsigned short eb = f2bf(acc_e);
                sA[0 * MT * ASTR + erow * ASTR + ej] = eb;
                sA[1 * MT * ASTR + erow * ASTR + ej] = eb;
                sA[0 * MT * ASTR + erow * ASTR + 144 + ej] = 0;
                sA[1 * MT * ASTR + erow * ASTR + 144 + ej] = 0;
            }
            // initial h = z[b]: 4 cols/thread
            const unsigned b_idx = (unsigned)gr / 5u;
            const float4 zv = *reinterpret_cast<const float4*>(z + (size_t)b_idx * 128 + ej * 4);
            union { u16x4 v4; unsigned short us[4]; } zz;
            zz.us[0]=f2bf(zv.x); zz.us[1]=f2bf(zv.y); zz.us[2]=f2bf(zv.z); zz.us[3]=f2bf(zv.w);
            *reinterpret_cast<u16x4*>(&sA[erow * ASTR + 16 + ej * 4]) = zz.v4;
        }

        float cst[4] = {0, 0, 0, 0};   // c state: els (row=2v+(e>>1), l=lane+64*(e&1))

        #pragma unroll
        for (int s = 0; s < HN; ++s) {
            const int cur = s & 1;
            const int nxt = cur ^ 1;
            __syncthreads();   // h(cur)/staging ready; prev-step sG reads done

            // ---- MFMA: this wave's 32 gate-cols over all 32 rows ----
            #pragma unroll
            for (int mt = 0; mt < 2; ++mt) {
                bf16x8 a[5];
                #pragma unroll
                for (int kt = 0; kt < 5; ++kt)
                    a[kt] = *reinterpret_cast<const bf16x8*>(
                        &sA[cur * MT * ASTR + (mt * 16 + cc) * ASTR + kt * 32 + quad * 8]);
                #pragma unroll
                for (int nt = 0; nt < 2; ++nt) {
                    f32x4 g = splat4(biasv[nt]);
                    #pragma unroll
                    for (int kt = 0; kt < 5; ++kt)
                        g = __builtin_amdgcn_mfma_f32_16x16x32_bf16(a[kt], Bf[nt][kt], g, 0, 0, 0);
                    // C layout: col = lane&15, row = quad*4 + r
                    const int base = (tg * 32 + mt * 16 + quad * 4) * GSTR + l0 + nt * 16 + cc;
                    #pragma unroll
                    for (int r = 0; r < 4; ++r) sG[base + r * GSTR] = g[r];
                }
            }

            __syncthreads();   // all gates in sG

            // ---- redistributed pointwise: 4 els/lane (rows 2v,2v+1) ----
            #pragma unroll
            for (int e = 0; e < 4; ++e) {
                const int row = 2 * v + (e >> 1);
                const int l   = lane + 64 * (e & 1);
                const float gi = sG[(0 * MT + row) * GSTR + l];   // -log2e * i_pre
                const float gf = sG[(1 * MT + row) * GSTR + l];   // -log2e * f_pre
                const float gg = sG[(2 * MT + row) * GSTR + l];   // 2log2e * g_pre
                const float go = sG[(3 * MT + row) * GSTR + l];   // -log2e * o_pre
                const float Ei = __builtin_amdgcn_exp2f(gi);
                const float Ef = __builtin_amdgcn_exp2f(gf);
                const float Eg = __builtin_amdgcn_exp2f(gg);
                const float Eo = __builtin_amdgcn_exp2f(go);
                const float t1  = (1.0f + Ei) * (1.0f + Eg);
                const float ef1 = 1.0f + Ef;
                const float num = fmaf(cst[e], t1, (Eg - 1.0f) * ef1);
                const float cn  = num * __builtin_amdgcn_rcpf(t1 * ef1);
                cst[e] = cn;
                const float Ec = __builtin_amdgcn_exp2f(2.0f * LOG2E * cn);
                const float hn = (Ec - 1.0f) *
                    __builtin_amdgcn_rcpf((1.0f + Eo) * (1.0f + Ec));
                sA[nxt * MT * ASTR + row * ASTR + 16 + l] = f2bf_fast(hn);
            }
        }

        __syncthreads();   // final h (buffer 1) complete

        // -------- epilogue: heads; 32 threads/row, 4 l each --------
        {
            const int row = erow;
            const u16x4 hv4 = *reinterpret_cast<const u16x4*>(
                &sA[1 * MT * ASTR + row * ASTR + 16 + ej * 4]);
            float p = 0.f, q0 = 0.f, q1 = 0.f, q2 = 0.f;
            #pragma unroll
            for (int u = 0; u < 4; ++u) {
                const int l = ej * 4 + u;
                const float hv = bf2f(hv4[u]);
                p  = fmaf(hv, sWp[l], p);
                q0 = fmaf(hv, sWr[l], q0);
                q1 = fmaf(hv, sWr[128 + l], q1);
                q2 = fmaf(hv, sWr[256 + l], q2);
            }
            #pragma unroll
            for (int m = 1; m < 32; m <<= 1) {
                p  += __shfl_xor(p,  m, 64);
                q0 += __shfl_xor(q0, m, 64);
                q1 += __shfl_xor(q1, m, 64);
                q2 += __shfl_xor(q2, m, 64);
            }
            if (ej == 0) {
                const int gr = r0g + row;
                const float prog  = p + bpv;
                const float rr0 = q0 + br0, rr1 = q1 + br1, rr2 = q2 + br2;
                const float rmean = (rr0 + rr1 + rr2) * (1.0f / 3.0f);
                const float s0 = sigm(rr0), s1 = sigm(rr1), s2 = sigm(rr2);
                const float sm = (s0 + s1 + s2) * (1.0f / 3.0f);
                const float d0 = s0 - sm, d1 = s1 - sm, d2 = s2 - sm;
                const float unc = (d0 * d0 + d1 * d1 + d2 * d2) * 0.5f;   // ddof=1
                out[gr]          = rmean;
                out[BK + gr]     = prog;
                out[2 * BK + gr] = unc;
                out[3 * BK + gr] = rr0;
                out[4 * BK + gr] = rr1;
                out[5 * BK + gr] = rr2;
            }
        }
        // next-tile staging writes sA emb/pad (both bufs) + buf0 h; epilogue
        // reads buf1 h-cols (disjoint). Step-0 barrier orders the rest.
    }
}

// NOTE: shfl_xor with m=32 crosses the row-halves (lanes 0-31 row A, 32-63 row B).
// That mixes two DIFFERENT rows' partials — so we must NOT include m=32 above.
// The loop above goes m=1..16 only if written `m < 32`? It's `m <<= 1` from 1
// while m < 32 -> m = 1,2,4,8,16. Correct: 32 threads per row are lanes
// [0,32) or [32,64); xor masks 1..16 stay within each half.

extern "C" void kernel_launch(void* const* d_in, const int* in_sizes, int n_in,
                              void* d_out, int out_size, void* d_ws, size_t ws_size,
                              hipStream_t stream) {
    const float* z       = (const float*)d_in[0];
    const float* anchors = (const float*)d_in[1];
    const float* W1      = (const float*)d_in[2];
    const float* b1      = (const float*)d_in[3];
    const float* W2      = (const float*)d_in[4];
    const float* b2      = (const float*)d_in[5];
    const float* Wih     = (const float*)d_in[6];
    const float* Whh     = (const float*)d_in[7];
    const float* bih     = (const float*)d_in[8];
    const float* bhh     = (const float*)d_in[9];
    const float* Wp      = (const float*)d_in[10];
    const float* bp      = (const float*)d_in[11];
    const float* Wr      = (const float*)d_in[12];
    const float* br      = (const float*)d_in[13];

    hipLaunchKernelGGL(wahead_kernel, dim3(WGS), dim3(THREADS), 0, stream,
                       z, anchors, W1, b1, W2, b2, Wih, Whh, bih, bhh,
                       Wp, bp, Wr, br, (float*)d_out);
}

// Round 10
// 215.852 us; speedup vs baseline: 1.2958x; 1.2958x over previous
//
#include <hip/hip_runtime.h>

// Problem constants
#define BN 32768
#define KN 5
#define LN 128
#define HN 3
#define ROWS (BN*KN)        // 163840
#define BK ROWS
#define MT 64               // rows per tile (two 32-row pipes)
#define TILES (ROWS/MT)     // 2560
#define WGS 512
#define TPW (TILES/WGS)     // 5 tiles per workgroup
#define THREADS 512         // 8 waves
#define ASTR 168            // A row stride bf16: [emb16|h128|zero16] + 8 pad
#define FSTR 136            // final-h buffer row stride bf16: 128 + 8 pad
#define LOG2E 1.44269504089f

using bf16x8 = __attribute__((ext_vector_type(8))) __bf16;
using bf16x2 = __attribute__((ext_vector_type(2))) __bf16;
using f32x4  = __attribute__((ext_vector_type(4))) float;
using u16x8  = __attribute__((ext_vector_type(8))) unsigned short;

__device__ inline unsigned short f2bf(float x) {
    union { float f; unsigned u; } v; v.f = x;
    unsigned r = v.u + 0x7FFFu + ((v.u >> 16) & 1u);   // RNE
    return (unsigned short)(r >> 16);
}
#if __has_builtin(__builtin_amdgcn_cvt_pk_bf16_f32)
__device__ inline unsigned short f2bf_fast(float x) {
    union { bf16x2 v; unsigned short us[2]; } u;
    u.v = __builtin_amdgcn_cvt_pk_bf16_f32(x, x);
    return u.us[0];
}
#else
__device__ inline unsigned short f2bf_fast(float x) { return f2bf(x); }
#endif
__device__ inline float bf2f(unsigned short b) {
    union { unsigned u; float f; } v; v.u = ((unsigned)b) << 16; return v.f;
}
__device__ inline float sigm(float x) {
    return __builtin_amdgcn_rcpf(1.0f + __builtin_amdgcn_exp2f(-LOG2E * x));
}
__device__ inline f32x4 splat4(float x) { f32x4 r; r[0]=x; r[1]=x; r[2]=x; r[3]=x; return r; }

__global__ __launch_bounds__(THREADS, 2)   // 256-reg cap: verified no-spill envelope
void wahead_kernel(const float* __restrict__ z,   const float* __restrict__ anchors,
                   const float* __restrict__ W1,  const float* __restrict__ b1,
                   const float* __restrict__ W2,  const float* __restrict__ b2,
                   const float* __restrict__ Wih, const float* __restrict__ Whh,
                   const float* __restrict__ bih, const float* __restrict__ bhh,
                   const float* __restrict__ Wp,  const float* __restrict__ bp,
                   const float* __restrict__ Wr,  const float* __restrict__ br,
                   float* __restrict__ out)
{
    __shared__ unsigned short sA[2 * MT * ASTR];   // ping-pong [emb|h|0] bf16, 43 KB
    __shared__ unsigned short sF[MT * FSTR];       // final-step h (bf16), 17 KB
    __shared__ float sW1[32], sb1[16], sW2[16 * 17], sb2[16], sWp[128], sWr[384];

    const int tid  = threadIdx.x;
    const int wv   = tid >> 6;       // wave 0..7: owns l-cols wv*16..wv*16+15 of each gate
    const int lane = tid & 63;
    const int quad = lane >> 4;
    const int cc   = lane & 15;

    // ---- stage small constant weights into LDS ----
    if (tid < 32)  sW1[tid] = W1[tid];
    if (tid < 16)  { sb1[tid] = b1[tid]; sb2[tid] = b2[tid]; }
    if (tid < 256) sW2[(tid >> 4) * 17 + (tid & 15)] = W2[tid];   // sW2[col*17+hh]
    if (tid < 128) sWp[tid] = Wp[tid];
    if (tid < 384) sWr[tid] = Wr[tid];

    // ---- stacked-B fragments [W_ih(16)|W_hh(128)|0(16)] with FOLDED gate scales ----
    // gates i,f,o scaled by -log2e; gate g by +2*log2e (exp2 applies to acc directly)
    // B layout (16x16x32): n = lane&15, k = quad*8 + j
    bf16x8 Bf[4][5];
    float  biasv[4];
    #pragma unroll
    for (int t = 0; t < 4; ++t) {
        const float sc = (t == 2) ? (2.0f * LOG2E) : (-LOG2E);
        const int n = t * 128 + wv * 16 + cc;
        biasv[t] = sc * (bih[n] + bhh[n]);
        #pragma unroll
        for (int kt = 0; kt < 5; ++kt) {
            const int k0 = kt * 32 + quad * 8;
            float v[8];
            if (k0 < 16) {
                const float4 p0 = *reinterpret_cast<const float4*>(Wih + n * 16 + k0);
                const float4 p1 = *reinterpret_cast<const float4*>(Wih + n * 16 + k0 + 4);
                v[0]=p0.x; v[1]=p0.y; v[2]=p0.z; v[3]=p0.w;
                v[4]=p1.x; v[5]=p1.y; v[6]=p1.z; v[7]=p1.w;
            } else if (k0 < 144) {
                const float4 p0 = *reinterpret_cast<const float4*>(Whh + n * 128 + (k0 - 16));
                const float4 p1 = *reinterpret_cast<const float4*>(Whh + n * 128 + (k0 - 16) + 4);
                v[0]=p0.x; v[1]=p0.y; v[2]=p0.z; v[3]=p0.w;
                v[4]=p1.x; v[5]=p1.y; v[6]=p1.z; v[7]=p1.w;
            } else {
                #pragma unroll
                for (int j = 0; j < 8; ++j) v[j] = 0.0f;
            }
            union { bf16x8 bv; unsigned short us[8]; } pk;
            #pragma unroll
            for (int j = 0; j < 8; ++j) pk.us[j] = f2bf(sc * v[j]);
            Bf[t][kt] = pk.bv;
        }
    }

    const float bpv = bp[0];
    const float br0 = br[0], br1 = br[1], br2 = br[2];

    f32x4 acc0[2][4], acc1[2][4];    // per-pipe accumulator banks
    float cst0[8], cst1[8];          // per-pipe c state

    // M(pipe): gates for 32 rows of `pipe` from sA[buf]
    auto do_mfma = [&](f32x4 (&acc)[2][4], int pipe, int buf) {
        #pragma unroll
        for (int mt = 0; mt < 2; ++mt)
            #pragma unroll
            for (int t = 0; t < 4; ++t) acc[mt][t] = splat4(biasv[t]);
        #pragma unroll
        for (int mt = 0; mt < 2; ++mt) {
            const int row = pipe * 32 + mt * 16 + cc;
            bf16x8 a[5];
            #pragma unroll
            for (int kt = 0; kt < 5; ++kt)
                a[kt] = *reinterpret_cast<const bf16x8*>(
                    &sA[buf * MT * ASTR + row * ASTR + kt * 32 + quad * 8]);
            #pragma unroll
            for (int kt = 0; kt < 5; ++kt)
                #pragma unroll
                for (int t = 0; t < 4; ++t)
                    acc[mt][t] = __builtin_amdgcn_mfma_f32_16x16x32_bf16(
                        a[kt], Bf[t][kt], acc[mt][t], 0, 0, 0);
        }
    };

    // W(pipe): LSTM pointwise on held acc; write h to sA[dstbuf] or (final) sF
    auto do_pw = [&](f32x4 (&acc)[2][4], float (&cst)[8], int pipe, int dstbuf,
                     bool final_h) {
        const int lcol = wv * 16 + cc;
        #pragma unroll
        for (int e = 0; e < 8; ++e) {
            const int mt = e >> 2, r = e & 3;
            const float Ei = __builtin_amdgcn_exp2f(acc[mt][0][r]);   // e^-i
            const float Ef = __builtin_amdgcn_exp2f(acc[mt][1][r]);   // e^-f
            const float Eg = __builtin_amdgcn_exp2f(acc[mt][2][r]);   // e^{2g}
            const float Eo = __builtin_amdgcn_exp2f(acc[mt][3][r]);   // e^-o
            const float t1  = (1.0f + Ei) * (1.0f + Eg);
            const float ef1 = 1.0f + Ef;
            const float num = fmaf(cst[e], t1, (Eg - 1.0f) * ef1);
            const float cn  = num * __builtin_amdgcn_rcpf(t1 * ef1);
            cst[e] = cn;
            const float Ec = __builtin_amdgcn_exp2f(2.0f * LOG2E * cn);
            const float hn = (Ec - 1.0f) *
                __builtin_amdgcn_rcpf((1.0f + Eo) * (1.0f + Ec));
            const int m = pipe * 32 + mt * 16 + quad * 4 + r;
            if (final_h) sF[m * FSTR + lcol] = f2bf_fast(hn);
            else         sA[dstbuf * MT * ASTR + m * ASTR + 16 + lcol] = f2bf_fast(hn);
        }
    };

    // staging: emb MLP + pads into both bufs, z -> buf0 h-cols
    auto do_stage = [&](int r0g) {
        const int erow = tid >> 3, esub = tid & 7;
        const int gr = r0g + erow;
        // issue global loads first (latency overlaps surrounding pointwise)
        const float ax = anchors[gr * 2], ay = anchors[gr * 2 + 1];
        const unsigned b_idx = (unsigned)gr / 5u;
        const float4* zp = reinterpret_cast<const float4*>(z + (size_t)b_idx * 128 + esub * 16);
        const float4 z0 = zp[0], z1 = zp[1], z2 = zp[2], z3 = zp[3];
        const int e0 = esub * 2;
        float a0 = sb2[e0], a1 = sb2[e0 + 1];
        #pragma unroll
        for (int hh = 0; hh < 16; ++hh) {
            float pre = fmaf(sW1[hh * 2], ax, fmaf(sW1[hh * 2 + 1], ay, sb1[hh]));
            pre = fmaxf(pre, 0.0f);
            a0 = fmaf(pre, sW2[e0 * 17 + hh], a0);
            a1 = fmaf(pre, sW2[(e0 + 1) * 17 + hh], a1);
        }
        const unsigned short b0 = f2bf(a0), b1v = f2bf(a1);
        #pragma unroll
        for (int bufi = 0; bufi < 2; ++bufi) {
            unsigned short* row = &sA[bufi * MT * ASTR + erow * ASTR];
            row[e0]       = b0;  row[e0 + 1]       = b1v;
            row[144 + e0] = 0;   row[144 + e0 + 1] = 0;
        }
        union { u16x8 v; unsigned short us[8]; } w0, w1;
        w0.us[0]=f2bf(z0.x); w0.us[1]=f2bf(z0.y); w0.us[2]=f2bf(z0.z); w0.us[3]=f2bf(z0.w);
        w0.us[4]=f2bf(z1.x); w0.us[5]=f2bf(z1.y); w0.us[6]=f2bf(z1.z); w0.us[7]=f2bf(z1.w);
        w1.us[0]=f2bf(z2.x); w1.us[1]=f2bf(z2.y); w1.us[2]=f2bf(z2.z); w1.us[3]=f2bf(z2.w);
        w1.us[4]=f2bf(z3.x); w1.us[5]=f2bf(z3.y); w1.us[6]=f2bf(z3.z); w1.us[7]=f2bf(z3.w);
        unsigned short* hrow = &sA[erow * ASTR + 16 + esub * 16];
        *reinterpret_cast<u16x8*>(hrow)     = w0.v;
        *reinterpret_cast<u16x8*>(hrow + 8) = w1.v;
    };

    // epilogue: heads from sF (bf16), 8 threads/row, 16 l each
    auto do_epi = [&](int r0g) {
        const int row = tid >> 3, j = tid & 7;
        const unsigned short* hrow = &sF[row * FSTR + j * 16];
        const u16x8 h0 = *reinterpret_cast<const u16x8*>(hrow);
        const u16x8 h1 = *reinterpret_cast<const u16x8*>(hrow + 8);
        float p = 0.f, q0 = 0.f, q1 = 0.f, q2 = 0.f;
        #pragma unroll
        for (int u = 0; u < 16; ++u) {
            const int l = j * 16 + u;
            const float hv = bf2f(u < 8 ? h0[u] : h1[u - 8]);
            p  = fmaf(hv, sWp[l], p);
            q0 = fmaf(hv, sWr[l], q0);
            q1 = fmaf(hv, sWr[128 + l], q1);
            q2 = fmaf(hv, sWr[256 + l], q2);
        }
        #pragma unroll
        for (int m = 1; m < 8; m <<= 1) {
            p  += __shfl_xor(p,  m, 64);
            q0 += __shfl_xor(q0, m, 64);
            q1 += __shfl_xor(q1, m, 64);
            q2 += __shfl_xor(q2, m, 64);
        }
        if (j == 0) {
            const int gr = r0g + row;
            const float prog  = p + bpv;
            const float rr0 = q0 + br0, rr1 = q1 + br1, rr2 = q2 + br2;
            const float rmean = (rr0 + rr1 + rr2) * (1.0f / 3.0f);
            const float s0 = sigm(rr0), s1 = sigm(rr1), s2 = sigm(rr2);
            const float sm = (s0 + s1 + s2) * (1.0f / 3.0f);
            const float d0 = s0 - sm, d1 = s1 - sm, d2 = s2 - sm;
            const float unc = (d0 * d0 + d1 * d1 + d2 * d2) * 0.5f;   // ddof=1
            out[gr]          = rmean;
            out[BK + gr]     = prog;
            out[2 * BK + gr] = unc;
            out[3 * BK + gr] = rr0;
            out[4 * BK + gr] = rr1;
            out[5 * BK + gr] = rr2;
        }
    };

    __syncthreads();   // consts staged

    int prev_r0g = 0;
    bool have_prev = false;

    #pragma unroll 1
    for (int ti = 0; ti < TPW; ++ti) {
        const int r0g = (blockIdx.x * TPW + ti) * MT;

        // ---- slot S: staging(t) ∥ final pointwise of P1(t-1) -> sF ----
        __syncthreads();
        do_stage(r0g);
        if (have_prev) do_pw(acc1, cst1, 1, 0, true);
        #pragma unroll
        for (int e = 0; e < 8; ++e) { cst0[e] = 0.0f; cst1[e] = 0.0f; }

        // ---- phase A: M(P0,s0); M(P1,s0) ∥ epilogue(t-1); then W(P0,s0) ----
        __syncthreads();
        do_mfma(acc0, 0, 0);
        do_mfma(acc1, 1, 0);
        if (have_prev) do_epi(prev_r0g);
        do_pw(acc0, cst0, 0, 1, false);          // -> buf1 rows 0-31

        // ---- phase B: M(P0,s1) ∥ W(P1,s0) ----
        __syncthreads();
        do_mfma(acc0, 0, 1);
        do_pw(acc1, cst1, 1, 1, false);          // -> buf1 rows 32-63

        // ---- phase C: M(P1,s1) ∥ W(P0,s1) ----
        __syncthreads();
        do_mfma(acc1, 1, 1);
        do_pw(acc0, cst0, 0, 0, false);          // -> buf0 rows 0-31

        // ---- phase D: M(P0,s2) ∥ W(P1,s1) ----
        __syncthreads();
        do_mfma(acc0, 0, 0);
        do_pw(acc1, cst1, 1, 0, false);          // -> buf0 rows 32-63

        // ---- phase E: M(P1,s2) ∥ W(P0,s2)->sF ----
        __syncthreads();
        do_mfma(acc1, 1, 0);
        do_pw(acc0, cst0, 0, 0, true);           // final h P0 -> sF rows 0-31

        have_prev = true;
        prev_r0g  = r0g;
    }

    // ---- drain: final P1 pointwise, then last epilogue ----
    __syncthreads();
    do_pw(acc1, cst1, 1, 0, true);               // final h P1 -> sF rows 32-63
    __syncthreads();
    do_epi(prev_r0g);
}

extern "C" void kernel_launch(void* const* d_in, const int* in_sizes, int n_in,
                              void* d_out, int out_size, void* d_ws, size_t ws_size,
                              hipStream_t stream) {
    const float* z       = (const float*)d_in[0];
    const float* anchors = (const float*)d_in[1];
    const float* W1      = (const float*)d_in[2];
    const float* b1      = (const float*)d_in[3];
    const float* W2      = (const float*)d_in[4];
    const float* b2      = (const float*)d_in[5];
    const float* Wih     = (const float*)d_in[6];
    const float* Whh     = (const float*)d_in[7];
    const float* bih     = (const float*)d_in[8];
    const float* bhh     = (const float*)d_in[9];
    const float* Wp      = (const float*)d_in[10];
    const float* bp      = (const float*)d_in[11];
    const float* Wr      = (const float*)d_in[12];
    const float* br      = (const float*)d_in[13];

    hipLaunchKernelGGL(wahead_kernel, dim3(WGS), dim3(THREADS), 0, stream,
                       z, anchors, W1, b1, W2, b2, Wih, Whh, bih, bhh,
                       Wp, bp, Wr, br, (float*)d_out);
}